// Round 1
// baseline (178.619 us; speedup 1.0000x reference)
//
#include <hip/hip_runtime.h>
#include <cstdint>

#define B_    4096
#define D_    256
#define KK_   6
#define T_    256
#define DEPTH_ 6
#define C_    8
#define F1    1536   // D*K
#define F2    3072   // 2*F1
#define NROW  1536   // T*DEPTH

__device__ inline float waveSum(float v) {
#pragma unroll
  for (int m = 32; m; m >>= 1) v += __shfl_xor(v, m, 64);
  return v;
}
__device__ inline int waveSumI(int v) {
#pragma unroll
  for (int m = 32; m; m >>= 1) v += __shfl_xor(v, m, 64);
  return v;
}

// ---------------------------------------------------------------------------
// K0: transform att_W (FIN,T) -> watt[t][f] = W[f,t]-W[f+F1,t], catt[t] = b_t + sum_f W[f+F1,t]
// ---------------------------------------------------------------------------
__global__ __launch_bounds__(256) void prep_att_kernel(
    const float* __restrict__ att_W, const float* __restrict__ att_b,
    float* __restrict__ watt, float* __restrict__ catt)
{
  const int t = blockIdx.x;
  float s = 0.f;
  for (int fme = threadIdx.x; fme < F1; fme += 256) {
    const float lo = att_W[(size_t)fme * T_ + t];
    const float hi = att_W[(size_t)(fme + F1) * T_ + t];
    watt[(size_t)t * F1 + fme] = lo - hi;
    s += hi;
  }
  __shared__ float rf[4];
  s = waveSum(s);
  if ((threadIdx.x & 63) == 0) rf[threadIdx.x >> 6] = s;
  __syncthreads();
  if (threadIdx.x == 0) catt[t] = rf[0] + rf[1] + rf[2] + rf[3] + att_b[t];
}

// ---------------------------------------------------------------------------
// K1: per-row sparsemax of sel_logits (Michelot), folded to sparse w + const c
// w[f] = relu(z[f]-tau) - relu(z[f+F1]-tau),  c = sum_f relu(z[f+F1]-tau)
// ---------------------------------------------------------------------------
__global__ __launch_bounds__(256) void sel_sparsemax_kernel(
    const float* __restrict__ sel_logits,
    float* __restrict__ w_val, unsigned short* __restrict__ w_idx,
    int* __restrict__ w_cnt, float* __restrict__ w_c)
{
  const int row = blockIdx.x;
  __shared__ float z[F2];
  __shared__ float rf[4];
  __shared__ int   ri[4];
  __shared__ float tau_sh;
  __shared__ int   cnt_sh;
  __shared__ int   scan_wave[4];

  const float* src = sel_logits + (size_t)row * F2;
  for (int i = threadIdx.x; i < F2; i += 256) z[i] = src[i];
  __syncthreads();

  const int wid  = threadIdx.x >> 6;
  const int lane = threadIdx.x & 63;

  float tau = -1e30f;
  float tau_next = 0.f;
  int cprev = F2 + 1;
  for (int it = 0; it < 64; ++it) {
    float s = 0.f; int c = 0;
    for (int i = threadIdx.x; i < F2; i += 256) {
      const float zi = z[i];
      if (zi > tau) { s += zi; c++; }
    }
    s = waveSum(s); c = waveSumI(c);
    if (lane == 0) { rf[wid] = s; ri[wid] = c; }
    __syncthreads();
    if (threadIdx.x == 0) {
      const float st = rf[0] + rf[1] + rf[2] + rf[3];
      const int   ct = ri[0] + ri[1] + ri[2] + ri[3];
      tau_sh = (st - 1.0f) / (float)ct;
      cnt_sh = ct;
    }
    __syncthreads();
    tau_next = tau_sh;
    const int cn = cnt_sh;
    __syncthreads();   // rf/ri/tau_sh free for next iteration
    if (cn == cprev) break;
    cprev = cn; tau = tau_next;
  }
  tau = tau_next;

  float chi = 0.f;
  float wv[6];
  int nnz = 0;
#pragma unroll
  for (int j = 0; j < 6; ++j) {
    const int fme = threadIdx.x + 256 * j;
    float lo = z[fme] - tau;       lo = lo > 0.f ? lo : 0.f;
    float hi = z[fme + F1] - tau;  hi = hi > 0.f ? hi : 0.f;
    chi += hi;
    wv[j] = lo - hi;
    if (wv[j] != 0.f) nnz++;
  }
  const float cs = waveSum(chi);
  if (lane == 0) rf[wid] = cs;

  // deterministic compaction: block exclusive scan over per-thread nnz
  int incl = nnz;
#pragma unroll
  for (int off = 1; off < 64; off <<= 1) {
    const int n = __shfl_up(incl, off, 64);
    if (lane >= off) incl += n;
  }
  if (lane == 63) scan_wave[wid] = incl;
  __syncthreads();
  if (threadIdx.x == 0) w_c[row] = rf[0] + rf[1] + rf[2] + rf[3];
  int wave_base = 0;
  for (int wp = 0; wp < wid; ++wp) wave_base += scan_wave[wp];
  int pos = wave_base + incl - nnz;
#pragma unroll
  for (int j = 0; j < 6; ++j) {
    if (wv[j] != 0.f) {
      w_val[(size_t)row * F1 + pos] = wv[j];
      w_idx[(size_t)row * F1 + pos] = (unsigned short)(threadIdx.x + 256 * j);
      pos++;
    }
  }
  if (threadIdx.x == 255) w_cnt[row] = pos;  // last thread's end == total
}

// ---------------------------------------------------------------------------
// K2: f[b, d*K+k] = sigmoid((x[b,d]-thr[d,k]) * exp(log_beta[d,k]))
// ---------------------------------------------------------------------------
__global__ __launch_bounds__(256) void f_kernel(
    const float* __restrict__ x, const float* __restrict__ thr,
    const float* __restrict__ log_beta, float* __restrict__ f)
{
  const int b = blockIdx.x;
  const int d = threadIdx.x;
  const float xv = x[(size_t)b * D_ + d];
#pragma unroll
  for (int k = 0; k < KK_; ++k) {
    const float beta = __expf(log_beta[d * KK_ + k]);
    const float tt = (xv - thr[d * KK_ + k]) * beta;
    const float s = 1.0f / (1.0f + __expf(-tt));
    f[(size_t)b * F1 + d * KK_ + k] = s;
  }
}

// ---------------------------------------------------------------------------
// K3: logits[b,t] = catt[t] + sum_f f[b,f]*watt[t,f]   (C = A * B^T, fp32)
// M=4096, N=256, K=1536; 64x64 tile, 256 threads, 4x4 microtile
// ---------------------------------------------------------------------------
__global__ __launch_bounds__(256) void gemm_logits_kernel(
    const float* __restrict__ A, const float* __restrict__ Bm,
    const float* __restrict__ catt, float* __restrict__ Cm)
{
  __shared__ __align__(16) float As[16][68];
  __shared__ __align__(16) float Bs[16][68];
  const int bm = blockIdx.x * 64;
  const int bn = blockIdx.y * 64;
  const int tid = threadIdx.x;
  const int ty = tid / 16, tx = tid % 16;
  const int lr = tid / 4;          // 0..63 row of tile
  const int lc = (tid % 4) * 4;    // k offset {0,4,8,12}
  float acc[4][4] = {};
  for (int k0 = 0; k0 < F1; k0 += 16) {
    const float4 a4 = *(const float4*)(A  + (size_t)(bm + lr) * F1 + k0 + lc);
    const float4 b4 = *(const float4*)(Bm + (size_t)(bn + lr) * F1 + k0 + lc);
    As[lc + 0][lr] = a4.x; As[lc + 1][lr] = a4.y; As[lc + 2][lr] = a4.z; As[lc + 3][lr] = a4.w;
    Bs[lc + 0][lr] = b4.x; Bs[lc + 1][lr] = b4.y; Bs[lc + 2][lr] = b4.z; Bs[lc + 3][lr] = b4.w;
    __syncthreads();
#pragma unroll
    for (int k = 0; k < 16; ++k) {
      const float4 av = *(const float4*)&As[k][ty * 4];
      const float4 bv = *(const float4*)&Bs[k][tx * 4];
      const float a_[4] = {av.x, av.y, av.z, av.w};
      const float b_[4] = {bv.x, bv.y, bv.z, bv.w};
#pragma unroll
      for (int i = 0; i < 4; ++i)
#pragma unroll
        for (int j = 0; j < 4; ++j) acc[i][j] += a_[i] * b_[j];
    }
    __syncthreads();
  }
#pragma unroll
  for (int i = 0; i < 4; ++i)
#pragma unroll
    for (int j = 0; j < 4; ++j)
      Cm[(size_t)(bm + ty * 4 + i) * T_ + bn + tx * 4 + j] = acc[i][j] + catt[bn + tx * 4 + j];
}

// ---------------------------------------------------------------------------
// K4: per-row sparsemax over T=256 (1 wave, Michelot) + compaction
// ---------------------------------------------------------------------------
__global__ __launch_bounds__(64) void att_sparsemax_kernel(
    const float* __restrict__ logits,
    unsigned short* __restrict__ a_idx, float* __restrict__ a_val,
    int* __restrict__ a_cnt)
{
  const int b = blockIdx.x;
  const int lane = threadIdx.x;
  float z[4];
#pragma unroll
  for (int j = 0; j < 4; ++j) z[j] = logits[(size_t)b * T_ + lane + 64 * j];
  float tau = -1e30f, taun = 0.f;
  int cprev = T_ + 1;
  for (int it = 0; it < 40; ++it) {
    float s = 0.f; int c = 0;
#pragma unroll
    for (int j = 0; j < 4; ++j) if (z[j] > tau) { s += z[j]; c++; }
    s = waveSum(s); c = waveSumI(c);
    taun = (s - 1.0f) / (float)c;
    if (c == cprev) break;
    cprev = c; tau = taun;
  }
  tau = taun;
  float av[4]; int nnz = 0;
#pragma unroll
  for (int j = 0; j < 4; ++j) {
    float a = z[j] - tau; av[j] = a > 0.f ? a : 0.f;
    if (av[j] > 0.f) nnz++;
  }
  int incl = nnz;
#pragma unroll
  for (int off = 1; off < 64; off <<= 1) {
    const int n = __shfl_up(incl, off, 64);
    if (lane >= off) incl += n;
  }
  int pos = incl - nnz;
#pragma unroll
  for (int j = 0; j < 4; ++j) {
    if (av[j] > 0.f) {
      a_idx[(size_t)b * T_ + pos] = (unsigned short)(lane + 64 * j);
      a_val[(size_t)b * T_ + pos] = av[j];
      pos++;
    }
  }
  if (lane == 63) a_cnt[b] = incl;
}

// ---------------------------------------------------------------------------
// K5: out[b,c] = sum over active t of a * sum_l prob_l * leaf[t,l,c]
//     prob_l computed per lane (lane == leaf index), p via sparse dots
// ---------------------------------------------------------------------------
__global__ __launch_bounds__(256) void final_kernel(
    const float* __restrict__ f,
    const float* __restrict__ w_val, const unsigned short* __restrict__ w_idx,
    const int* __restrict__ w_cnt, const float* __restrict__ w_c,
    const unsigned short* __restrict__ a_idx, const float* __restrict__ a_val,
    const int* __restrict__ a_cnt,
    const float* __restrict__ leaf, float* __restrict__ out)
{
  const int b = blockIdx.x;
  __shared__ float fl[F1];
  __shared__ float oacc[4][C_];
  const int tid = threadIdx.x;
  const int wid = tid >> 6, lane = tid & 63;
  for (int i = tid; i < F1; i += 256) fl[i] = f[(size_t)b * F1 + i];
  __syncthreads();
  const int nact = a_cnt[b];
  float o[C_];
#pragma unroll
  for (int c = 0; c < C_; ++c) o[c] = 0.f;

  for (int i = wid; i < nact; i += 4) {
    const int t = a_idx[(size_t)b * T_ + i];
    const float aval = a_val[(size_t)b * T_ + i];
    float p[DEPTH_];
#pragma unroll
    for (int d = 0; d < DEPTH_; ++d) {
      const int row = t * DEPTH_ + d;
      const int nn = w_cnt[row];
      const float* wv = w_val + (size_t)row * F1;
      const unsigned short* wi = w_idx + (size_t)row * F1;
      float s = 0.f;
      for (int j = lane; j < nn; j += 64) s += wv[j] * fl[wi[j]];
      s = waveSum(s);
      float pv = w_c[row] + s;
      pv = pv < 1e-6f ? 1e-6f : (pv > 1.0f - 1e-6f ? 1.0f - 1e-6f : pv);
      p[d] = pv;
    }
    float prob = aval;
#pragma unroll
    for (int d = 0; d < DEPTH_; ++d) prob *= ((lane >> d) & 1) ? p[d] : (1.0f - p[d]);
    const float* lf = leaf + ((size_t)t * 64 + lane) * C_;
#pragma unroll
    for (int c = 0; c < C_; ++c) o[c] += prob * lf[c];
  }
#pragma unroll
  for (int c = 0; c < C_; ++c) o[c] = waveSum(o[c]);
  if (lane == 0) {
#pragma unroll
    for (int c = 0; c < C_; ++c) oacc[wid][c] = o[c];
  }
  __syncthreads();
  if (tid < C_)
    out[(size_t)b * C_ + tid] = oacc[0][tid] + oacc[1][tid] + oacc[2][tid] + oacc[3][tid];
}

// ---------------------------------------------------------------------------
extern "C" void kernel_launch(void* const* d_in, const int* in_sizes, int n_in,
                              void* d_out, int out_size, void* d_ws, size_t ws_size,
                              hipStream_t stream)
{
  const float* x        = (const float*)d_in[0];
  const float* thr      = (const float*)d_in[1];
  const float* log_beta = (const float*)d_in[2];
  const float* sel      = (const float*)d_in[3];
  const float* leaf     = (const float*)d_in[4];
  const float* att_W    = (const float*)d_in[5];
  const float* att_b    = (const float*)d_in[6];
  float* out = (float*)d_out;

  char* ws = (char*)d_ws;
  size_t off = 0;
  auto alloc = [&](size_t bytes) {
    char* p = ws + off;
    off = (off + bytes + 255) & ~(size_t)255;
    return p;
  };
  float*          f      = (float*)alloc((size_t)B_ * F1 * 4);           // 25.2 MB
  float*          watt   = (float*)alloc((size_t)T_ * F1 * 4);           //  1.6 MB
  float*          catt   = (float*)alloc((size_t)T_ * 4);
  float*          w_val  = (float*)alloc((size_t)NROW * F1 * 4);         //  9.4 MB
  unsigned short* w_idx  = (unsigned short*)alloc((size_t)NROW * F1 * 2);//  4.7 MB
  int*            w_cnt  = (int*)alloc((size_t)NROW * 4);
  float*          w_c    = (float*)alloc((size_t)NROW * 4);
  float*          logits = (float*)alloc((size_t)B_ * T_ * 4);           //  4.2 MB
  unsigned short* a_idx  = (unsigned short*)alloc((size_t)B_ * T_ * 2);  //  2.1 MB
  float*          a_val  = (float*)alloc((size_t)B_ * T_ * 4);           //  4.2 MB
  int*            a_cnt  = (int*)alloc((size_t)B_ * 4);
  (void)ws_size; (void)in_sizes; (void)n_in; (void)out_size;             // ~51.5 MB total

  hipLaunchKernelGGL(prep_att_kernel,      dim3(T_),            dim3(256), 0, stream, att_W, att_b, watt, catt);
  hipLaunchKernelGGL(sel_sparsemax_kernel, dim3(NROW),          dim3(256), 0, stream, sel, w_val, w_idx, w_cnt, w_c);
  hipLaunchKernelGGL(f_kernel,             dim3(B_),            dim3(256), 0, stream, x, thr, log_beta, f);
  hipLaunchKernelGGL(gemm_logits_kernel,   dim3(B_ / 64, T_ / 64), dim3(256), 0, stream, f, watt, catt, logits);
  hipLaunchKernelGGL(att_sparsemax_kernel, dim3(B_),            dim3(64),  0, stream, logits, a_idx, a_val, a_cnt);
  hipLaunchKernelGGL(final_kernel,         dim3(B_),            dim3(256), 0, stream, f, w_val, w_idx, w_cnt, w_c, a_idx, a_val, a_cnt, leaf, out);
}

// Round 2
// 131.666 us; speedup vs baseline: 1.3566x; 1.3566x over previous
//
#include <hip/hip_runtime.h>
#include <cstdint>

#define B_     4096
#define D_     256
#define KK_    6
#define T_     256
#define DEPTH_ 6
#define C_     8
#define F1     1536   // D*K
#define F2     3072   // 2*F1
#define NROW   1536   // T*DEPTH
#define KSEG   1536
#define KTOT   4608   // 3 segments: hi*hi, hi*lo, lo*hi
#define SPLITK 2
#define KSPL   2304   // KTOT / SPLITK
#define BK     64
#define NIT    (KSPL / BK)   // 36
#define NFB    24     // F1/64 blocks for prep_att

using bf16x8 = __attribute__((ext_vector_type(8))) __bf16;
using f32x4  = __attribute__((ext_vector_type(4))) float;

__device__ inline float waveSum(float v) {
#pragma unroll
  for (int m = 32; m; m >>= 1) v += __shfl_xor(v, m, 64);
  return v;
}
__device__ inline int waveSumI(int v) {
#pragma unroll
  for (int m = 32; m; m >>= 1) v += __shfl_xor(v, m, 64);
  return v;
}

__device__ __forceinline__ void gload_lds16(const void* g, void* l) {
  __builtin_amdgcn_global_load_lds(
      (const __attribute__((address_space(1))) unsigned int*)g,
      (__attribute__((address_space(3))) unsigned int*)l, 16, 0, 0);
}

// ---------------------------------------------------------------------------
// K0a: tile-transpose att_W -> watt hi/lo bf16 [T][F1]; partial catt col sums
// watt[t][f] = W[f][t] - W[f+F1][t];  pc[fb][t] = sum_{f in blk} W[f+F1][t]
// ---------------------------------------------------------------------------
__global__ __launch_bounds__(256) void prep_att_kernel(
    const float* __restrict__ att_W,
    __bf16* __restrict__ w_hi, __bf16* __restrict__ w_lo,
    float* __restrict__ pc)
{
  const int fblk = blockIdx.x * 64;   // over F1
  const int tblk = blockIdx.y * 64;   // over T
  __shared__ float Wl[64][65], Wh[64][65];
  const int tt = threadIdx.x & 63;
  const int f4 = threadIdx.x >> 6;
#pragma unroll
  for (int r = 0; r < 16; ++r) {
    const int f = r * 4 + f4;
    Wl[f][tt] = att_W[(size_t)(fblk + f) * T_ + tblk + tt];
    Wh[f][tt] = att_W[(size_t)(fblk + f + F1) * T_ + tblk + tt];
  }
  __syncthreads();
  const int t  = threadIdx.x >> 2;
  const int fq = threadIdx.x & 3;
#pragma unroll
  for (int pass = 0; pass < 4; ++pass) {
    const int f0 = pass * 16 + fq * 4;
    alignas(8) __bf16 hv[4];
    alignas(8) __bf16 lv[4];
#pragma unroll
    for (int e = 0; e < 4; ++e) {
      const float w = Wl[f0 + e][t] - Wh[f0 + e][t];
      const __bf16 h = (__bf16)w;
      hv[e] = h;
      lv[e] = (__bf16)(w - (float)h);
    }
    *(uint2*)&w_hi[(size_t)(tblk + t) * F1 + fblk + f0] = *(const uint2*)hv;
    *(uint2*)&w_lo[(size_t)(tblk + t) * F1 + fblk + f0] = *(const uint2*)lv;
  }
  if (threadIdx.x < 64) {
    float s = 0.f;
#pragma unroll
    for (int f = 0; f < 64; ++f) s += Wh[f][threadIdx.x];
    pc[(size_t)blockIdx.x * T_ + tblk + threadIdx.x] = s;
  }
}

__global__ __launch_bounds__(256) void catt_kernel(
    const float* __restrict__ pc, const float* __restrict__ att_b,
    float* __restrict__ catt)
{
  const int t = threadIdx.x;
  float s = att_b[t];
  for (int i = 0; i < NFB; ++i) s += pc[(size_t)i * T_ + t];
  catt[t] = s;
}

// ---------------------------------------------------------------------------
// K1: per-row sparsemax of sel_logits (Michelot), folded to sparse w + const c
// ---------------------------------------------------------------------------
__global__ __launch_bounds__(256) void sel_sparsemax_kernel(
    const float* __restrict__ sel_logits,
    float* __restrict__ w_val, unsigned short* __restrict__ w_idx,
    int* __restrict__ w_cnt, float* __restrict__ w_c)
{
  const int row = blockIdx.x;
  __shared__ float z[F2];
  __shared__ float rf[4];
  __shared__ int   ri[4];
  __shared__ float tau_sh;
  __shared__ int   cnt_sh;
  __shared__ int   scan_wave[4];

  const float* src = sel_logits + (size_t)row * F2;
  for (int i = threadIdx.x; i < F2; i += 256) z[i] = src[i];
  __syncthreads();

  const int wid  = threadIdx.x >> 6;
  const int lane = threadIdx.x & 63;

  float tau = -1e30f;
  float tau_next = 0.f;
  int cprev = F2 + 1;
  for (int it = 0; it < 64; ++it) {
    float s = 0.f; int c = 0;
    for (int i = threadIdx.x; i < F2; i += 256) {
      const float zi = z[i];
      if (zi > tau) { s += zi; c++; }
    }
    s = waveSum(s); c = waveSumI(c);
    if (lane == 0) { rf[wid] = s; ri[wid] = c; }
    __syncthreads();
    if (threadIdx.x == 0) {
      const float st = rf[0] + rf[1] + rf[2] + rf[3];
      const int   ct = ri[0] + ri[1] + ri[2] + ri[3];
      tau_sh = (st - 1.0f) / (float)ct;
      cnt_sh = ct;
    }
    __syncthreads();
    tau_next = tau_sh;
    const int cn = cnt_sh;
    __syncthreads();
    if (cn == cprev) break;
    cprev = cn; tau = tau_next;
  }
  tau = tau_next;

  float chi = 0.f;
  float wv[6];
  int nnz = 0;
#pragma unroll
  for (int j = 0; j < 6; ++j) {
    const int fme = threadIdx.x + 256 * j;
    float lo = z[fme] - tau;       lo = lo > 0.f ? lo : 0.f;
    float hi = z[fme + F1] - tau;  hi = hi > 0.f ? hi : 0.f;
    chi += hi;
    wv[j] = lo - hi;
    if (wv[j] != 0.f) nnz++;
  }
  const float cs = waveSum(chi);
  if (lane == 0) rf[wid] = cs;

  int incl = nnz;
#pragma unroll
  for (int off = 1; off < 64; off <<= 1) {
    const int n = __shfl_up(incl, off, 64);
    if (lane >= off) incl += n;
  }
  if (lane == 63) scan_wave[wid] = incl;
  __syncthreads();
  if (threadIdx.x == 0) w_c[row] = rf[0] + rf[1] + rf[2] + rf[3];
  int wave_base = 0;
  for (int wp = 0; wp < wid; ++wp) wave_base += scan_wave[wp];
  int pos = wave_base + incl - nnz;
#pragma unroll
  for (int j = 0; j < 6; ++j) {
    if (wv[j] != 0.f) {
      w_val[(size_t)row * F1 + pos] = wv[j];
      w_idx[(size_t)row * F1 + pos] = (unsigned short)(threadIdx.x + 256 * j);
      pos++;
    }
  }
  if (threadIdx.x == 255) w_cnt[row] = pos;
}

// ---------------------------------------------------------------------------
// K2: f = sigmoid((x-thr)*exp(log_beta)) -> bf16 hi/lo pair [B][F1]
// ---------------------------------------------------------------------------
__global__ __launch_bounds__(256) void f_kernel(
    const float* __restrict__ x, const float* __restrict__ thr,
    const float* __restrict__ log_beta,
    __bf16* __restrict__ f_hi, __bf16* __restrict__ f_lo)
{
  const int b = blockIdx.x;
  const int d = threadIdx.x;
  const float xv = x[(size_t)b * D_ + d];
#pragma unroll
  for (int k = 0; k < KK_; ++k) {
    const float beta = __expf(log_beta[d * KK_ + k]);
    const float tt = (xv - thr[d * KK_ + k]) * beta;
    const float s = 1.0f / (1.0f + __expf(-tt));
    const __bf16 h = (__bf16)s;
    f_hi[(size_t)b * F1 + d * KK_ + k] = h;
    f_lo[(size_t)b * F1 + d * KK_ + k] = (__bf16)(s - (float)h);
  }
}

// ---------------------------------------------------------------------------
// K3: MFMA GEMM, part[sp][b][t] = sum over split-K of bf16-split products.
// K = 4608 = [f_hi*w_hi | f_hi*w_lo | f_lo*w_hi].  64x64 tile, BK=64,
// 4 waves (2x2), each 32x32 via 2x2 mfma_f32_16x16x32_bf16 frags.
// LDS: linear dest for global_load_lds + inverse-XOR-swizzled source;
// ds_read uses matching XOR swizzle (byte ^= (row&7)<<4).
// ---------------------------------------------------------------------------
__global__ __launch_bounds__(256) void gemm_mfma_kernel(
    const __bf16* __restrict__ f_hi, const __bf16* __restrict__ f_lo,
    const __bf16* __restrict__ w_hi, const __bf16* __restrict__ w_lo,
    float* __restrict__ part)
{
  __shared__ __bf16 As[2][64 * 64];
  __shared__ __bf16 Bs[2][64 * 64];
  const int bm = blockIdx.x * 64;
  const int bn = blockIdx.y * 64;
  const int sp = blockIdx.z;
  const int tid = threadIdx.x;
  const int wid = tid >> 6, lane = tid & 63;
  const int wr = wid >> 1, wc = wid & 1;

  // staging constants: chunk q covers LDS bytes [q*1024, q*1024+1024)
  // lane l -> row = q*8 + (l>>3), phys kb = (l&7)*16, logical kb = phys ^ ((row&7)<<4)
  const int srow = lane >> 3;
  const int skb8 = ((lane & 7) ^ srow) << 3;   // element offset of 16B chunk

  // frag ds_read byte offsets (kiter-invariant)
  const int l15   = lane & 15;
  const int mask  = (lane & 7) << 4;
  const int khalf = (lane >> 4) << 4;
  int offA[2][2], offB[2][2];
#pragma unroll
  for (int m = 0; m < 2; ++m) {
    const int row = wr * 32 + m * 16 + l15;
#pragma unroll
    for (int s = 0; s < 2; ++s)
      offA[m][s] = row * 128 + (((s << 6) | khalf) ^ mask);
  }
#pragma unroll
  for (int n = 0; n < 2; ++n) {
    const int col = wc * 32 + n * 16 + l15;
#pragma unroll
    for (int s = 0; s < 2; ++s)
      offB[n][s] = col * 128 + (((s << 6) | khalf) ^ mask);
  }

  f32x4 acc[2][2] = {};

  auto stage = [&](int it, int buf) {
    const int k0  = sp * KSPL + it * BK;
    const int seg = k0 / KSEG;
    const int kl  = k0 - seg * KSEG;
    const __bf16* __restrict__ asrc = (seg < 2) ? f_hi : f_lo;
    const __bf16* __restrict__ bsrc = (seg == 1) ? w_lo : w_hi;
#pragma unroll
    for (int j = 0; j < 2; ++j) {
      const int q = wid * 2 + j;
      gload_lds16(asrc + (size_t)(bm + q * 8 + srow) * F1 + kl + skb8, &As[buf][q * 512]);
      gload_lds16(bsrc + (size_t)(bn + q * 8 + srow) * F1 + kl + skb8, &Bs[buf][q * 512]);
    }
  };

  stage(0, 0);
  __syncthreads();
  for (int it = 0; it < NIT; ++it) {
    const int cur = it & 1;
    if (it + 1 < NIT) stage(it + 1, cur ^ 1);
    const char* pa = (const char*)As[cur];
    const char* pb = (const char*)Bs[cur];
#pragma unroll
    for (int s = 0; s < 2; ++s) {
      const bf16x8 a0 = *(const bf16x8*)(pa + offA[0][s]);
      const bf16x8 a1 = *(const bf16x8*)(pa + offA[1][s]);
      const bf16x8 b0 = *(const bf16x8*)(pb + offB[0][s]);
      const bf16x8 b1 = *(const bf16x8*)(pb + offB[1][s]);
      acc[0][0] = __builtin_amdgcn_mfma_f32_16x16x32_bf16(a0, b0, acc[0][0], 0, 0, 0);
      acc[0][1] = __builtin_amdgcn_mfma_f32_16x16x32_bf16(a0, b1, acc[0][1], 0, 0, 0);
      acc[1][0] = __builtin_amdgcn_mfma_f32_16x16x32_bf16(a1, b0, acc[1][0], 0, 0, 0);
      acc[1][1] = __builtin_amdgcn_mfma_f32_16x16x32_bf16(a1, b1, acc[1][1], 0, 0, 0);
    }
    __syncthreads();
  }

  const int r0 = (lane >> 4) << 2;
  float* outp = part + (size_t)sp * B_ * T_;
#pragma unroll
  for (int m = 0; m < 2; ++m)
#pragma unroll
    for (int n = 0; n < 2; ++n)
#pragma unroll
      for (int r = 0; r < 4; ++r)
        outp[(size_t)(bm + wr * 32 + m * 16 + r0 + r) * T_ + (bn + wc * 32 + n * 16 + l15)] =
            acc[m][n][r];
}

// ---------------------------------------------------------------------------
// K4: fused split-K reduce + catt + per-row sparsemax over T=256 + compaction
// ---------------------------------------------------------------------------
__global__ __launch_bounds__(64) void att_sparsemax_kernel(
    const float* __restrict__ part, const float* __restrict__ catt,
    unsigned short* __restrict__ a_idx, float* __restrict__ a_val,
    int* __restrict__ a_cnt)
{
  const int b = blockIdx.x;
  const int lane = threadIdx.x;
  float z[4];
#pragma unroll
  for (int j = 0; j < 4; ++j) {
    const int t = lane + 64 * j;
    z[j] = part[(size_t)b * T_ + t] + part[((size_t)B_ + b) * T_ + t] + catt[t];
  }
  float tau = -1e30f, taun = 0.f;
  int cprev = T_ + 1;
  for (int it = 0; it < 40; ++it) {
    float s = 0.f; int c = 0;
#pragma unroll
    for (int j = 0; j < 4; ++j) if (z[j] > tau) { s += z[j]; c++; }
    s = waveSum(s); c = waveSumI(c);
    taun = (s - 1.0f) / (float)c;
    if (c == cprev) break;
    cprev = c; tau = taun;
  }
  tau = taun;
  float av[4]; int nnz = 0;
#pragma unroll
  for (int j = 0; j < 4; ++j) {
    float a = z[j] - tau; av[j] = a > 0.f ? a : 0.f;
    if (av[j] > 0.f) nnz++;
  }
  int incl = nnz;
#pragma unroll
  for (int off = 1; off < 64; off <<= 1) {
    const int n = __shfl_up(incl, off, 64);
    if (lane >= off) incl += n;
  }
  int pos = incl - nnz;
#pragma unroll
  for (int j = 0; j < 4; ++j) {
    if (av[j] > 0.f) {
      a_idx[(size_t)b * T_ + pos] = (unsigned short)(lane + 64 * j);
      a_val[(size_t)b * T_ + pos] = av[j];
      pos++;
    }
  }
  if (lane == 63) a_cnt[b] = incl;
}

// ---------------------------------------------------------------------------
// K5: out[b,c] = sum over active t of a * sum_l prob_l * leaf[t,l,c]
// ---------------------------------------------------------------------------
__global__ __launch_bounds__(256) void final_kernel(
    const __bf16* __restrict__ f_hi, const __bf16* __restrict__ f_lo,
    const float* __restrict__ w_val, const unsigned short* __restrict__ w_idx,
    const int* __restrict__ w_cnt, const float* __restrict__ w_c,
    const unsigned short* __restrict__ a_idx, const float* __restrict__ a_val,
    const int* __restrict__ a_cnt,
    const float* __restrict__ leaf, float* __restrict__ out)
{
  const int b = blockIdx.x;
  __shared__ float fl[F1];
  __shared__ float oacc[4][C_];
  const int tid = threadIdx.x;
  const int wid = tid >> 6, lane = tid & 63;
  for (int i = tid; i < F1; i += 256)
    fl[i] = (float)f_hi[(size_t)b * F1 + i] + (float)f_lo[(size_t)b * F1 + i];
  __syncthreads();
  const int nact = a_cnt[b];
  float o[C_];
#pragma unroll
  for (int c = 0; c < C_; ++c) o[c] = 0.f;

  for (int i = wid; i < nact; i += 4) {
    const int t = a_idx[(size_t)b * T_ + i];
    const float aval = a_val[(size_t)b * T_ + i];
    float p[DEPTH_];
#pragma unroll
    for (int d = 0; d < DEPTH_; ++d) {
      const int row = t * DEPTH_ + d;
      const int nn = w_cnt[row];
      const float* wv = w_val + (size_t)row * F1;
      const unsigned short* wi = w_idx + (size_t)row * F1;
      float s = 0.f;
      for (int j = lane; j < nn; j += 64) s += wv[j] * fl[wi[j]];
      s = waveSum(s);
      float pv = w_c[row] + s;
      pv = pv < 1e-6f ? 1e-6f : (pv > 1.0f - 1e-6f ? 1.0f - 1e-6f : pv);
      p[d] = pv;
    }
    float prob = aval;
#pragma unroll
    for (int d = 0; d < DEPTH_; ++d) prob *= ((lane >> d) & 1) ? p[d] : (1.0f - p[d]);
    const float* lf = leaf + ((size_t)t * 64 + lane) * C_;
#pragma unroll
    for (int c = 0; c < C_; ++c) o[c] += prob * lf[c];
  }
#pragma unroll
  for (int c = 0; c < C_; ++c) o[c] = waveSum(o[c]);
  if (lane == 0) {
#pragma unroll
    for (int c = 0; c < C_; ++c) oacc[wid][c] = o[c];
  }
  __syncthreads();
  if (tid < C_)
    out[(size_t)b * C_ + tid] = oacc[0][tid] + oacc[1][tid] + oacc[2][tid] + oacc[3][tid];
}

// ---------------------------------------------------------------------------
extern "C" void kernel_launch(void* const* d_in, const int* in_sizes, int n_in,
                              void* d_out, int out_size, void* d_ws, size_t ws_size,
                              hipStream_t stream)
{
  const float* x        = (const float*)d_in[0];
  const float* thr      = (const float*)d_in[1];
  const float* log_beta = (const float*)d_in[2];
  const float* sel      = (const float*)d_in[3];
  const float* leaf     = (const float*)d_in[4];
  const float* att_W    = (const float*)d_in[5];
  const float* att_b    = (const float*)d_in[6];
  float* out = (float*)d_out;

  char* ws = (char*)d_ws;
  size_t off = 0;
  auto alloc = [&](size_t bytes) {
    char* p = ws + off;
    off = (off + bytes + 255) & ~(size_t)255;
    return p;
  };
  __bf16*         f_hi   = (__bf16*)alloc((size_t)B_ * F1 * 2);          // 12.6 MB
  __bf16*         f_lo   = (__bf16*)alloc((size_t)B_ * F1 * 2);          // 12.6 MB
  __bf16*         w_hi   = (__bf16*)alloc((size_t)T_ * F1 * 2);          //  0.8 MB
  __bf16*         w_lo   = (__bf16*)alloc((size_t)T_ * F1 * 2);          //  0.8 MB
  float*          catt   = (float*)alloc((size_t)T_ * 4);
  float*          pc     = (float*)alloc((size_t)NFB * T_ * 4);
  float*          w_val  = (float*)alloc((size_t)NROW * F1 * 4);         //  9.4 MB
  unsigned short* w_idx  = (unsigned short*)alloc((size_t)NROW * F1 * 2);//  4.7 MB
  int*            w_cnt  = (int*)alloc((size_t)NROW * 4);
  float*          w_c    = (float*)alloc((size_t)NROW * 4);
  float*          part   = (float*)alloc((size_t)SPLITK * B_ * T_ * 4);  //  8.4 MB
  unsigned short* a_idx  = (unsigned short*)alloc((size_t)B_ * T_ * 2);  //  2.1 MB
  float*          a_val  = (float*)alloc((size_t)B_ * T_ * 4);           //  4.2 MB
  int*            a_cnt  = (int*)alloc((size_t)B_ * 4);
  (void)ws_size; (void)in_sizes; (void)n_in; (void)out_size;             // ~56 MB total

  hipLaunchKernelGGL(prep_att_kernel,      dim3(NFB, T_ / 64),        dim3(256), 0, stream, att_W, w_hi, w_lo, pc);
  hipLaunchKernelGGL(catt_kernel,          dim3(1),                   dim3(256), 0, stream, pc, att_b, catt);
  hipLaunchKernelGGL(sel_sparsemax_kernel, dim3(NROW),                dim3(256), 0, stream, sel, w_val, w_idx, w_cnt, w_c);
  hipLaunchKernelGGL(f_kernel,             dim3(B_),                  dim3(256), 0, stream, x, thr, log_beta, f_hi, f_lo);
  hipLaunchKernelGGL(gemm_mfma_kernel,     dim3(B_ / 64, T_ / 64, SPLITK), dim3(256), 0, stream, f_hi, f_lo, w_hi, w_lo, part);
  hipLaunchKernelGGL(att_sparsemax_kernel, dim3(B_),                  dim3(64),  0, stream, part, catt, a_idx, a_val, a_cnt);
  hipLaunchKernelGGL(final_kernel,         dim3(B_),                  dim3(256), 0, stream, f_hi, f_lo, w_val, w_idx, w_cnt, w_c, a_idx, a_val, a_cnt, leaf, out);
}